// Round 13
// baseline (109.495 us; speedup 1.0000x reference)
//
#include <hip/hip_runtime.h>
#include <hip/hip_bf16.h>
#include <stdint.h>

// out_re[b,i] = sum_{j,l} Re{ x[b,j,l]*k[i,j]*conj(k[i,l]) },  d_out = Re only.
//   T_re = P·R + Q·M ; T_im = P·M + Q·(-R)  (A = K-frags, B = X), then
//   out_re[b,i] = sum_j T_re*p[i,j] - T_im*q[i,j].
// Round-13: depth-2 DMA pipeline. 3 X buffers (LDS = KP 32K | KQ 32K | X 3x32K
// = 160KB, AITER-proven on gfx950); phase g: WAITV(8) -> barrier -> compute ->
// barrier -> STAGE(g+3). Each stage now has ~2 compute phases (≫900cyc HBM
// latency) to land, vs round-12's single-barrier window (the ~84% WAITV stall).
// Global stores moved OUT of the loop (per-batch results in o[n] regs, one
// burst at the end) so the vmcnt queue is pure DMA and counted waits are exact.

typedef __attribute__((ext_vector_type(8))) __bf16 bf16x8;
typedef __attribute__((ext_vector_type(4))) float f32x4;
typedef __attribute__((ext_vector_type(4))) unsigned int u32x4;

#define EDIM 128
#define FRAG_ELEMS 16384    // ws bf16 elems: P[0,16384) Q[16384,32768)
#define NBAT 8
#define NPH (NBAT * 4)      // 32 global phases per block
#define LDS_BYTES 163840
#define KQ_OFF 32768
#define X_OFF 65536
#define XBUF 32768
#define XM_OFF 16384

static __device__ inline bf16x8 neg8(bf16x8 v) {
    u32x4 u = __builtin_bit_cast(u32x4, v);
    u ^= (u32x4){0x80008000u, 0x80008000u, 0x80008000u, 0x80008000u};
    return __builtin_bit_cast(bf16x8, u);
}

// ---- pre-pass: K (f32 interleaved p,q) -> bf16 fragment streams P, Q ----
// frag f = nT*4+u; lane (li,s) holds K[nT*16+li][u*32+s*8 .. +8)
__global__ void kprep_kernel(const float* __restrict__ Kern, __bf16* __restrict__ kf)
{
    int id = blockIdx.x * 256 + threadIdx.x;    // 0..2047
    int f    = id >> 6;
    int lane = id & 63;
    int nT = f >> 2, u = f & 3;
    int li = lane & 15, s = lane >> 4;
    int i  = nT * 16 + li;
    int l0 = u * 32 + s * 8;
    const float* g = Kern + (((size_t)i * EDIM + l0) << 1);
    bf16x8 p, q;
#pragma unroll
    for (int e = 0; e < 8; ++e) {
        p[e] = (__bf16)g[2 * e];
        q[e] = (__bf16)g[2 * e + 1];
    }
    ((bf16x8*)kf)[id]                = p;
    ((bf16x8*)(kf + FRAG_ELEMS))[id] = q;
}

#define ASG(p) (__attribute__((address_space(1))) const void*)(p)
#define ASL(p) (__attribute__((address_space(3))) void*)(p)
#define WAITV(N_) asm volatile("s_waitcnt vmcnt(" #N_ ")" ::: "memory")
#define BARRIER() asm volatile("s_barrier" ::: "memory")

__global__ __launch_bounds__(512, 2) void qmeas_kernel(
    const float* __restrict__ R, const float* __restrict__ M,
    const __bf16* __restrict__ kf, float* __restrict__ out, int nout)
{
    extern __shared__ unsigned char smem[];   // KP 32K | KQ 32K | X0 | X1 | X2

    const int t    = threadIdx.x;
    const int lane = t & 63;
    const int w    = t >> 6;       // wave 0..7 = i-tile
    const int li   = lane & 15;
    const int s    = lane >> 4;    // 0..3
    const int rhi  = lane >> 5;    // 0..1 (staging row-within-pair)
    const int key  = li & 7;       // X swizzle key on read
    const int bat0 = blockIdx.x * NBAT;

    // ---- K-frag DMA: ws -> LDS linear copy (8 x 1KB per wave) ----
#pragma unroll
    for (int kk = 0; kk < 8; ++kk) {
        int base = ((w << 3) + kk) * 1024;
        const unsigned char* src = (const unsigned char*)kf + base + lane * 16;
        __builtin_amdgcn_global_load_lds(ASG(src), ASL(smem + base), 16, 0, 0);
    }

    // stage global phase g_: batch bat0+(g_>>2), j-quarter (g_&3), buf g_%3
#define STAGE_G(g_)                                                             \
    do {                                                                        \
        const size_t xb_ = (size_t)(bat0 + ((g_) >> 2)) * (EDIM * EDIM);        \
        unsigned char* db_ = smem + X_OFF + ((g_) % 3) * XBUF;                  \
        _Pragma("unroll")                                                       \
        for (int k2 = 0; k2 < 2; ++k2) {                                        \
            int rloc = (w << 2) + (k2 << 1);                                    \
            int rowg = ((g_) & 3) * 32 + rloc + rhi;                            \
            int colf = ((lane & 31) ^ ((rloc + rhi) & 7)) << 2;                 \
            const float* sR_ = R + xb_ + (size_t)rowg * EDIM + colf;            \
            const float* sM_ = M + xb_ + (size_t)rowg * EDIM + colf;            \
            unsigned char* d_ = db_ + rloc * 512;                               \
            __builtin_amdgcn_global_load_lds(ASG(sR_), ASL(d_), 16, 0, 0);      \
            __builtin_amdgcn_global_load_lds(ASG(sM_), ASL(d_ + XM_OFF), 16, 0, 0); \
        }                                                                       \
    } while (0)

    STAGE_G(0);
    STAGE_G(1);
    STAGE_G(2);

    float reS[4] = {0.f, 0.f, 0.f, 0.f};
    f32x4 o[NBAT];

    // compute+fold j-quarter phase p_ (0..3) from buf_; acc = 16 regs
#define COMPUTE_FOLD(p_, buf_)                                                  \
    do {                                                                        \
        const unsigned char* Xb = smem + X_OFF + (buf_) * XBUF;                 \
        f32x4 are[2], aim[2];                                                   \
        are[0] = (f32x4){0.f,0.f,0.f,0.f}; are[1] = (f32x4){0.f,0.f,0.f,0.f};   \
        aim[0] = (f32x4){0.f,0.f,0.f,0.f}; aim[1] = (f32x4){0.f,0.f,0.f,0.f};   \
        _Pragma("unroll")                                                       \
        for (int u = 0; u < 4; ++u) {                                           \
            bf16x8 pa = *(const bf16x8*)(smem + ((w << 2) + u) * 1024 + lane * 16); \
            bf16x8 qa = *(const bf16x8*)(smem + KQ_OFF + ((w << 2) + u) * 1024 + lane * 16); \
            _Pragma("unroll")                                                   \
            for (int jt = 0; jt < 2; ++jt) {                                    \
                int rl = (jt << 4) + li;                                        \
                int c0 = (u << 3) + (s << 1);                                   \
                int a0 = rl * 512 + ((c0 ^ key) << 4);                          \
                int a1 = rl * 512 + (((c0 + 1) ^ key) << 4);                    \
                f32x4 r0 = *(const f32x4*)(Xb + a0);                            \
                f32x4 r1 = *(const f32x4*)(Xb + a1);                            \
                f32x4 m0 = *(const f32x4*)(Xb + XM_OFF + a0);                   \
                f32x4 m1 = *(const f32x4*)(Xb + XM_OFF + a1);                   \
                bf16x8 xr, xm;                                                  \
                _Pragma("unroll")                                               \
                for (int e = 0; e < 4; ++e) {                                   \
                    xr[e] = (__bf16)r0[e]; xr[4 + e] = (__bf16)r1[e];           \
                    xm[e] = (__bf16)m0[e]; xm[4 + e] = (__bf16)m1[e];           \
                }                                                               \
                bf16x8 xrn = neg8(xr);                                          \
                are[jt] = __builtin_amdgcn_mfma_f32_16x16x32_bf16(pa, xr,  are[jt], 0, 0, 0); \
                are[jt] = __builtin_amdgcn_mfma_f32_16x16x32_bf16(qa, xm,  are[jt], 0, 0, 0); \
                aim[jt] = __builtin_amdgcn_mfma_f32_16x16x32_bf16(pa, xm,  aim[jt], 0, 0, 0); \
                aim[jt] = __builtin_amdgcn_mfma_f32_16x16x32_bf16(qa, xrn, aim[jt], 0, 0, 0); \
            }                                                                   \
        }                                                                       \
        const __bf16* KPb = (const __bf16*)smem;                                \
        const __bf16* KQb = (const __bf16*)(smem + KQ_OFF);                     \
        _Pragma("unroll")                                                       \
        for (int jt = 0; jt < 2; ++jt) {                                        \
            int lanep = ((( jt << 1) + (li >> 3)) & 3) << 4;                    \
            int fbase = (((w << 2) + (p_)) << 6) + lanep + (s << 2);            \
            _Pragma("unroll")                                                   \
            for (int r = 0; r < 4; ++r) {                                       \
                int ei = ((fbase + r) << 3) + (li & 7);                         \
                float pw = (float)KPb[ei], qw = (float)KQb[ei];                 \
                reS[r] += are[jt][r] * pw - aim[jt][r] * qw;                    \
            }                                                                   \
        }                                                                       \
    } while (0)

#pragma unroll
    for (int n = 0; n < NBAT; ++n) {
#pragma unroll
        for (int p = 0; p < 4; ++p) {
            const int g = n * 4 + p;
            if (g < NPH - 2)       WAITV(8);   // drain stage g; g+1,g+2 in flight
            else if (g == NPH - 2) WAITV(4);
            else                   WAITV(0);
            BARRIER();                          // stage g visible to all waves
            COMPUTE_FOLD(p, g % 3);
            BARRIER();                          // buf g%3 fully consumed
            if (g + 3 < NPH) STAGE_G(g + 3);    // reuses buf g%3, WAR-safe
        }
        // batch done: reduce reS over li, stash in regs (no VMEM in loop!)
#pragma unroll
        for (int r = 0; r < 4; ++r) {
            reS[r] += __shfl_xor(reS[r], 1);
            reS[r] += __shfl_xor(reS[r], 2);
            reS[r] += __shfl_xor(reS[r], 4);
            reS[r] += __shfl_xor(reS[r], 8);
        }
        o[n][0] = reS[0]; o[n][1] = reS[1]; o[n][2] = reS[2]; o[n][3] = reS[3];
        reS[0] = reS[1] = reS[2] = reS[3] = 0.f;
    }

    // ---- single store burst at the end ----
    if (li == 0) {
#pragma unroll
        for (int n = 0; n < NBAT; ++n) {
            int oi = (bat0 + n) * EDIM + (w << 4) + (s << 2);
            if (oi + 3 < nout) *(f32x4*)(out + oi) = o[n];
        }
    }
}

extern "C" void kernel_launch(void* const* d_in, const int* in_sizes, int n_in,
                              void* d_out, int out_size, void* d_ws, size_t ws_size,
                              hipStream_t stream) {
    const float* R    = (const float*)d_in[0];
    const float* M    = (const float*)d_in[1];
    const float* Kern = (const float*)d_in[2];
    float*       out  = (float*)d_out;
    __bf16*      kf   = (__bf16*)d_ws;          // needs 64KB of ws
    const int    B    = in_sizes[0] / (EDIM * EDIM);   // 2048

    hipFuncSetAttribute((const void*)qmeas_kernel,
                        hipFuncAttributeMaxDynamicSharedMemorySize, LDS_BYTES);

    kprep_kernel<<<8, 256, 0, stream>>>(Kern, kf);
    int grid = B / NBAT;   // 256
    qmeas_kernel<<<grid, 512, LDS_BYTES, stream>>>(R, M, kf, out, out_size);
}

// Round 14
// 69.065 us; speedup vs baseline: 1.5854x; 1.5854x over previous
//
#include <hip/hip_runtime.h>
#include <hip/hip_bf16.h>
#include <stdint.h>

// out_re[b,i] = sum_{j,l} Re{ x[b,j,l]*k[i,j]*conj(k[i,l]) },  d_out = Re only.
//   T_re = P·R + Q·M ; T_im = P·M + Q·(-R)  (A = K-frags, B = X), then
//   out_re[b,i] = sum_j T_re*p[i,j] - T_im*q[i,j].
// Round-14: depth-3 DMA pipeline, ROLLED batch loop (round-13's regression was
// 32 inlined COMPUTE_FOLD copies = 60KB code > 32KB I$; round-12 = 4 copies).
// 3 X buffers rotate with period 3 (m0,m1,m2 += 1 per batch, 4 ≡ 1 mod 3);
// only vmcnt immediates need compile-time p, so 4 explicit phases in a rolled
// loop. Stores in-loop (no o[] array -> no dynamic reg indexing). vmcnt ledger
// verified: steady WAITV(8) exact at p2/p3, +1 conservative at p0/p1; tail
// 8/8/4/0; prologue WAITV(8) drains K-DMA + stage0 exactly.

typedef __attribute__((ext_vector_type(8))) __bf16 bf16x8;
typedef __attribute__((ext_vector_type(4))) float f32x4;
typedef __attribute__((ext_vector_type(4))) unsigned int u32x4;

#define EDIM 128
#define FRAG_ELEMS 16384    // ws bf16 elems: P[0,16384) Q[16384,32768)
#define NBAT 8
#define LDS_BYTES 163840
#define KQ_OFF 32768
#define X_OFF 65536
#define XBUF 32768
#define XM_OFF 16384

static __device__ inline bf16x8 neg8(bf16x8 v) {
    u32x4 u = __builtin_bit_cast(u32x4, v);
    u ^= (u32x4){0x80008000u, 0x80008000u, 0x80008000u, 0x80008000u};
    return __builtin_bit_cast(bf16x8, u);
}

// ---- pre-pass: K (f32 interleaved p,q) -> bf16 fragment streams P, Q ----
// frag f = nT*4+u; lane (li,s) holds K[nT*16+li][u*32+s*8 .. +8)
__global__ void kprep_kernel(const float* __restrict__ Kern, __bf16* __restrict__ kf)
{
    int id = blockIdx.x * 256 + threadIdx.x;    // 0..2047
    int f    = id >> 6;
    int lane = id & 63;
    int nT = f >> 2, u = f & 3;
    int li = lane & 15, s = lane >> 4;
    int i  = nT * 16 + li;
    int l0 = u * 32 + s * 8;
    const float* g = Kern + (((size_t)i * EDIM + l0) << 1);
    bf16x8 p, q;
#pragma unroll
    for (int e = 0; e < 8; ++e) {
        p[e] = (__bf16)g[2 * e];
        q[e] = (__bf16)g[2 * e + 1];
    }
    ((bf16x8*)kf)[id]                = p;
    ((bf16x8*)(kf + FRAG_ELEMS))[id] = q;
}

#define ASG(p) (__attribute__((address_space(1))) const void*)(p)
#define ASL(p) (__attribute__((address_space(3))) void*)(p)
#define WAITV(N_) asm volatile("s_waitcnt vmcnt(" #N_ ")" ::: "memory")
#define BARRIER() asm volatile("s_barrier" ::: "memory")

__global__ __launch_bounds__(512, 2) void qmeas_kernel(
    const float* __restrict__ R, const float* __restrict__ M,
    const __bf16* __restrict__ kf, float* __restrict__ out, int nout)
{
    extern __shared__ unsigned char smem[];   // KP 32K | KQ 32K | X0 | X1 | X2

    const int t    = threadIdx.x;
    const int lane = t & 63;
    const int w    = t >> 6;       // wave 0..7 = i-tile
    const int li   = lane & 15;
    const int s    = lane >> 4;    // 0..3
    const int rhi  = lane >> 5;    // 0..1 (staging row-within-pair)
    const int key  = li & 7;       // X swizzle key on read
    const int bat0 = blockIdx.x * NBAT;

    // ---- K-frag DMA: ws -> LDS linear copy (8 x 1KB per wave) ----
#pragma unroll
    for (int kk = 0; kk < 8; ++kk) {
        int base = ((w << 3) + kk) * 1024;
        const unsigned char* src = (const unsigned char*)kf + base + lane * 16;
        __builtin_amdgcn_global_load_lds(ASG(src), ASL(smem + base), 16, 0, 0);
    }

    // stage j-quarter q_ of batch base xb_ into LDS offset xo_; 4 DMA/wave
#define STAGE_X(xb_, q_, xo_)                                                   \
    do {                                                                        \
        unsigned char* db_ = smem + (xo_);                                      \
        _Pragma("unroll")                                                       \
        for (int k2 = 0; k2 < 2; ++k2) {                                        \
            int rloc = (w << 2) + (k2 << 1);                                    \
            int rowg = (q_) * 32 + rloc + rhi;                                  \
            int colf = ((lane & 31) ^ ((rloc + rhi) & 7)) << 2;                 \
            const float* sR_ = R + (xb_) + (size_t)rowg * EDIM + colf;          \
            const float* sM_ = M + (xb_) + (size_t)rowg * EDIM + colf;          \
            unsigned char* d_ = db_ + rloc * 512;                               \
            __builtin_amdgcn_global_load_lds(ASG(sR_), ASL(d_), 16, 0, 0);      \
            __builtin_amdgcn_global_load_lds(ASG(sM_), ASL(d_ + XM_OFF), 16, 0, 0); \
        }                                                                       \
    } while (0)

    // compute+fold j-quarter phase p_ (compile-time) from LDS offset xo_
#define COMPUTE_FOLD(p_, xo_)                                                   \
    do {                                                                        \
        const unsigned char* Xb = smem + (xo_);                                 \
        f32x4 are[2], aim[2];                                                   \
        are[0] = (f32x4){0.f,0.f,0.f,0.f}; are[1] = (f32x4){0.f,0.f,0.f,0.f};   \
        aim[0] = (f32x4){0.f,0.f,0.f,0.f}; aim[1] = (f32x4){0.f,0.f,0.f,0.f};   \
        _Pragma("unroll")                                                       \
        for (int u = 0; u < 4; ++u) {                                           \
            bf16x8 pa = *(const bf16x8*)(smem + ((w << 2) + u) * 1024 + lane * 16); \
            bf16x8 qa = *(const bf16x8*)(smem + KQ_OFF + ((w << 2) + u) * 1024 + lane * 16); \
            _Pragma("unroll")                                                   \
            for (int jt = 0; jt < 2; ++jt) {                                    \
                int rl = (jt << 4) + li;                                        \
                int c0 = (u << 3) + (s << 1);                                   \
                int a0 = rl * 512 + ((c0 ^ key) << 4);                          \
                int a1 = rl * 512 + (((c0 + 1) ^ key) << 4);                    \
                f32x4 r0 = *(const f32x4*)(Xb + a0);                            \
                f32x4 r1 = *(const f32x4*)(Xb + a1);                            \
                f32x4 m0 = *(const f32x4*)(Xb + XM_OFF + a0);                   \
                f32x4 m1 = *(const f32x4*)(Xb + XM_OFF + a1);                   \
                bf16x8 xr, xm;                                                  \
                _Pragma("unroll")                                               \
                for (int e = 0; e < 4; ++e) {                                   \
                    xr[e] = (__bf16)r0[e]; xr[4 + e] = (__bf16)r1[e];           \
                    xm[e] = (__bf16)m0[e]; xm[4 + e] = (__bf16)m1[e];           \
                }                                                               \
                bf16x8 xrn = neg8(xr);                                          \
                are[jt] = __builtin_amdgcn_mfma_f32_16x16x32_bf16(pa, xr,  are[jt], 0, 0, 0); \
                are[jt] = __builtin_amdgcn_mfma_f32_16x16x32_bf16(qa, xm,  are[jt], 0, 0, 0); \
                aim[jt] = __builtin_amdgcn_mfma_f32_16x16x32_bf16(pa, xm,  aim[jt], 0, 0, 0); \
                aim[jt] = __builtin_amdgcn_mfma_f32_16x16x32_bf16(qa, xrn, aim[jt], 0, 0, 0); \
            }                                                                   \
        }                                                                       \
        const __bf16* KPb = (const __bf16*)smem;                                \
        const __bf16* KQb = (const __bf16*)(smem + KQ_OFF);                     \
        _Pragma("unroll")                                                       \
        for (int jt = 0; jt < 2; ++jt) {                                        \
            int lanep = ((( jt << 1) + (li >> 3)) & 3) << 4;                    \
            int fbase = (((w << 2) + (p_)) << 6) + lanep + (s << 2);            \
            _Pragma("unroll")                                                   \
            for (int r = 0; r < 4; ++r) {                                       \
                int ei = ((fbase + r) << 3) + (li & 7);                         \
                float pw = (float)KPb[ei], qw = (float)KQb[ei];                 \
                reS[r] += are[jt][r] * pw - aim[jt][r] * qw;                    \
            }                                                                   \
        }                                                                       \
    } while (0)

    // prologue: stage batch 0, quarters 0,1,2 into bufs 0,1,2
    size_t xb = (size_t)bat0 * (EDIM * EDIM);
    STAGE_X(xb, 0, X_OFF + 0 * XBUF);
    STAGE_X(xb, 1, X_OFF + 1 * XBUF);
    STAGE_X(xb, 2, X_OFF + 2 * XBUF);

    float reS[4] = {0.f, 0.f, 0.f, 0.f};
    int m0 = 0, m1 = 1, m2 = 2;   // buffer rotation: +1 per batch (4 ≡ 1 mod 3)

#pragma unroll 1
    for (int n = 0; n < NBAT; ++n) {
        const size_t xbn  = (size_t)(bat0 + n) * (EDIM * EDIM);
        const size_t xbn1 = xbn + (size_t)(EDIM * EDIM);
        const int    xo0  = X_OFF + m0 * XBUF;
        const int    xo1  = X_OFF + m1 * XBUF;
        const int    xo2  = X_OFF + m2 * XBUF;
        const bool   more = (n < NBAT - 1);

        // p0: compute q0 from m0; stage (n, q3) -> m0
        WAITV(8); BARRIER();
        COMPUTE_FOLD(0, xo0);
        BARRIER();
        STAGE_X(xbn, 3, xo0);

        // p1: compute q1 from m1; stage (n+1, q0) -> m1
        WAITV(8); BARRIER();
        COMPUTE_FOLD(1, xo1);
        BARRIER();
        if (more) STAGE_X(xbn1, 0, xo1);

        // p2: compute q2 from m2; stage (n+1, q1) -> m2
        if (more) { WAITV(8); } else { WAITV(4); }
        BARRIER();
        COMPUTE_FOLD(2, xo2);
        BARRIER();
        if (more) STAGE_X(xbn1, 1, xo2);

        // p3: compute q3 from m0 (restaged at p0); store; stage (n+1, q2) -> m0
        if (more) { WAITV(8); } else { WAITV(0); }
        BARRIER();
        COMPUTE_FOLD(3, xo0);
#pragma unroll
        for (int r = 0; r < 4; ++r) {
            reS[r] += __shfl_xor(reS[r], 1);
            reS[r] += __shfl_xor(reS[r], 2);
            reS[r] += __shfl_xor(reS[r], 4);
            reS[r] += __shfl_xor(reS[r], 8);
        }
        if (li == 0) {
            int oi = (bat0 + n) * EDIM + (w << 4) + (s << 2);
            if (oi + 3 < nout) {
                f32x4 o;
                o[0] = reS[0]; o[1] = reS[1]; o[2] = reS[2]; o[3] = reS[3];
                *(f32x4*)(out + oi) = o;
            }
        }
        reS[0] = reS[1] = reS[2] = reS[3] = 0.f;
        BARRIER();
        if (more) STAGE_X(xbn1, 2, xo0);

        // rotate buffers
        int tmp = m0; m0 = m1; m1 = m2; m2 = tmp;
    }
}

extern "C" void kernel_launch(void* const* d_in, const int* in_sizes, int n_in,
                              void* d_out, int out_size, void* d_ws, size_t ws_size,
                              hipStream_t stream) {
    const float* R    = (const float*)d_in[0];
    const float* M    = (const float*)d_in[1];
    const float* Kern = (const float*)d_in[2];
    float*       out  = (float*)d_out;
    __bf16*      kf   = (__bf16*)d_ws;          // needs 64KB of ws
    const int    B    = in_sizes[0] / (EDIM * EDIM);   // 2048

    hipFuncSetAttribute((const void*)qmeas_kernel,
                        hipFuncAttributeMaxDynamicSharedMemorySize, LDS_BYTES);

    kprep_kernel<<<8, 256, 0, stream>>>(Kern, kf);
    int grid = B / NBAT;   // 256
    qmeas_kernel<<<grid, 512, LDS_BYTES, stream>>>(R, M, kf, out, out_size);
}